// Round 3
// baseline (1574.083 us; speedup 1.0000x reference)
//
#include <hip/hip_runtime.h>
#include <hip/hip_bf16.h>

#define HW   4096
#define HDIM 64
#define WDIM 64

// Static device workspace (element offsets into g_ws):
#define OFF_A  0                       // 2*50*HW   = 409600
#define OFF_B  409600                  // 2*98*HW   = 802816
#define WS_A1  1212416                 // 2*64*HW   = 524288
#define WS_A2  1736704
#define WS_B1  2260992
#define WS_B2  2785280
#define WT_A1  3309568                 // 9*64*24   = 13824
#define WT_A2  3323392                 // 25*64*56  = 89600
#define WT_B1  3412992                 // 25*64*56  = 89600
#define WT_B2  3502592                 // 49*64*104 = 326144
#define WS_TOT 3828736

__device__ float g_ws[WS_TOT];

// ---------------------------------------------------------------------------
// Weight prep: wg (Cout, 64, K, K) fp32 -> g_ws[wt_off] as [tap][ci][co],
// co padded to Cp with zeros.
// ---------------------------------------------------------------------------
__global__ __launch_bounds__(256) void prep_w_kernel(const float* __restrict__ wg,
                                                     int wt_off,
                                                     int Cout, int Cp, int KK) {
    float* wt = g_ws + wt_off;
    int n = KK * 64 * Cp;
    for (int idx = blockIdx.x * 256 + threadIdx.x; idx < n; idx += gridDim.x * 256) {
        int co  = idx % Cp;
        int ci  = (idx / Cp) % 64;
        int tap = idx / (Cp * 64);
        float v = 0.f;
        if (co < Cout) v = wg[(co * 64 + ci) * KK + tap];
        wt[idx] = v;
    }
}

// ---------------------------------------------------------------------------
// Offset conv: dense conv Cin=64 -> Cout, kernel K, stride 1, pad, dil.
// src = src_ext (real input) if non-null else g_ws + src_off.
// dst = g_ws + dst_off, laid out (B, Cout, HW) fp32.
// Block 256 = 64 w-lanes x 4 h rows; each thread computes 8 couts.
// grid: (32, ceil(Cout/8))
// ---------------------------------------------------------------------------
template<int K, int CP>
__global__ __launch_bounds__(256) void offconv_kernel(
    const float* __restrict__ src_ext, int src_off, int bstride,
    int wt_off, const float* __restrict__ bias,
    int dst_off, int Cout, int pad, int dil)
{
    const float* src = src_ext ? src_ext : (const float*)(g_ws + src_off);
    const float* wt  = g_ws + wt_off;
    float*       dst = g_ws + dst_off;

    const int tid = threadIdx.x;
    const int w   = tid & 63;
    const int dh  = tid >> 6;
    const int bx  = blockIdx.x;             // 0..31
    const int b   = bx >> 4;
    const int h   = ((bx & 15) << 2) | dh;
    const int co0 = blockIdx.y << 3;

    float acc[8];
#pragma unroll
    for (int j = 0; j < 8; ++j) acc[j] = 0.f;

    const float* sb = src + (long)b * bstride;
    for (int ci = 0; ci < 64; ++ci) {
        const float* sc = sb + ci * HW;
#pragma unroll
        for (int ky = 0; ky < K; ++ky) {
            const int ih = h - pad + ky * dil;
            const bool rowok = ((unsigned)ih < 64u);
            const float* sr = sc + ih * 64;
#pragma unroll
            for (int kx = 0; kx < K; ++kx) {
                const int iw = w - pad + kx * dil;
                float val = (rowok && ((unsigned)iw < 64u)) ? sr[iw] : 0.f;
                const float* wr = wt + ((ky * K + kx) * 64 + ci) * CP + co0;
#pragma unroll
                for (int j = 0; j < 8; ++j) acc[j] = fmaf(val, wr[j], acc[j]);
            }
        }
    }

    float* dro = dst + (long)b * Cout * HW + h * 64 + w;
#pragma unroll
    for (int j = 0; j < 8; ++j) {
        const int co = co0 + j;
        if (co < Cout) dro[co * HW] = acc[j] + bias[co];
    }
}

// ---------------------------------------------------------------------------
// Depthwise deformable sampling.
// out[b,c,h,w] = sum_kk wdw[c,kk] * bilinear(src[b,c], py, px), zero outside.
// off channels: 2kk = y-offset, 2kk+1 = x-offset (fp32 in g_ws).
// Block 256 = 4 waves x 64 w-lanes; each wave handles 4 channels.
// grid: (B*H = 128, 4)
// ---------------------------------------------------------------------------
template<int K>
__global__ __launch_bounds__(256) void deform_kernel(
    const float* __restrict__ src_ext, int src_off, int bstride,
    int off_off, const float* __restrict__ wdw,
    int dst_off, int pad, int dil)
{
    constexpr int KK = K * K;
    const float* src = src_ext ? src_ext : (const float*)(g_ws + src_off);
    const float* off = g_ws + off_off;
    float*       dst = g_ws + dst_off;

    const int tid = threadIdx.x;
    const int w   = tid & 63;
    const int b   = blockIdx.x >> 6;
    const int h   = blockIdx.x & 63;
    const int c0  = (int)(blockIdx.y << 4) + ((tid >> 6) << 2);

    const float* offb = off + (long)b * (2 * KK) * HW + h * 64 + w;
    const float* sb   = src + (long)b * bstride + (long)c0 * HW;

    float acc[4] = {0.f, 0.f, 0.f, 0.f};

    for (int kk = 0; kk < KK; ++kk) {
        const float oy = offb[(2 * kk) * HW];
        const float ox = offb[(2 * kk + 1) * HW];
        const float py = oy + (float)(h - pad + (kk / K) * dil);
        const float px = ox + (float)(w - pad + (kk % K) * dil);
        const float fy = floorf(py), fx = floorf(px);
        const float ly = py - fy,    lx = px - fx;
        const int y0 = (int)fy, x0 = (int)fx;
        const int y1 = y0 + 1,  x1 = x0 + 1;
        const float vy0 = ((unsigned)y0 < 64u) ? 1.f : 0.f;
        const float vy1 = ((unsigned)y1 < 64u) ? 1.f : 0.f;
        const float vx0 = ((unsigned)x0 < 64u) ? 1.f : 0.f;
        const float vx1 = ((unsigned)x1 < 64u) ? 1.f : 0.f;
        const float w00 = (1.f - ly) * (1.f - lx) * vy0 * vx0;
        const float w01 = (1.f - ly) * lx         * vy0 * vx1;
        const float w10 = ly         * (1.f - lx) * vy1 * vx0;
        const float w11 = ly         * lx         * vy1 * vx1;
        const int y0c = min(max(y0, 0), 63), y1c = min(max(y1, 0), 63);
        const int x0c = min(max(x0, 0), 63), x1c = min(max(x1, 0), 63);
        const int i00 = y0c * 64 + x0c, i01 = y0c * 64 + x1c;
        const int i10 = y1c * 64 + x0c, i11 = y1c * 64 + x1c;
#pragma unroll
        for (int j = 0; j < 4; ++j) {
            const float* sc = sb + j * HW;
            float val = w00 * sc[i00] + w01 * sc[i01]
                      + w10 * sc[i10] + w11 * sc[i11];
            acc[j] = fmaf(wdw[(c0 + j) * KK + kk], val, acc[j]);
        }
    }

    float* dp = dst + ((long)b * 64 + c0) * HW + h * 64 + w;
#pragma unroll
    for (int j = 0; j < 4; ++j) dp[j * HW] = acc[j];
}

// ---------------------------------------------------------------------------
// Final: per-branch 1x1 conv (+bias), then out = x * result.  fp32 out.
// grid: (4096/256, 128/8, B); block 256. Each thread: 1 pixel x 8 couts.
// ---------------------------------------------------------------------------
__global__ __launch_bounds__(256) void final_kernel(
    const float* __restrict__ x,
    int aA_off, int aB_off,
    const float* __restrict__ w1, const float* __restrict__ b1,
    const float* __restrict__ w2, const float* __restrict__ b2,
    float* __restrict__ out)
{
    __shared__ float wlds[512];
    const int tid = threadIdx.x;
    const int p   = blockIdx.x * 256 + tid;
    const int co0 = blockIdx.y << 3;
    const int b   = blockIdx.z;
    const bool brB = (co0 >= 64);
    const int  cl0 = co0 & 63;
    const float* a  = g_ws + (brB ? aB_off : aA_off);
    const float* wg = brB ? w2 : w1;
    const float* bg = brB ? b2 : b1;

    for (int e = tid; e < 512; e += 256) {
        int ci = e >> 3, j = e & 7;
        wlds[e] = wg[(cl0 + j) * 64 + ci];
    }
    __syncthreads();

    float acc[8] = {0, 0, 0, 0, 0, 0, 0, 0};
    const float* ab = a + (long)b * 64 * HW + p;
    for (int ci = 0; ci < 64; ++ci) {
        const float av = ab[ci * HW];
        const float* wr = &wlds[ci * 8];
#pragma unroll
        for (int j = 0; j < 8; ++j) acc[j] = fmaf(av, wr[j], acc[j]);
    }

    const float* xb = x   + ((long)b * 128 + co0) * HW + p;
    float*       ob = out + ((long)b * 128 + co0) * HW + p;
#pragma unroll
    for (int j = 0; j < 8; ++j) {
        ob[j * HW] = (acc[j] + bg[cl0 + j]) * xb[j * HW];
    }
}

// ---------------------------------------------------------------------------
extern "C" void kernel_launch(void* const* d_in, const int* in_sizes, int n_in,
                              void* d_out, int out_size, void* d_ws, size_t ws_size,
                              hipStream_t stream) {
    const float* x         = (const float*)d_in[0];
    const float* cv0_off_w = (const float*)d_in[1];
    const float* cv0_off_b = (const float*)d_in[2];
    const float* cv0_w     = (const float*)d_in[3];
    const float* cvs_off_w = (const float*)d_in[4];
    const float* cvs_off_b = (const float*)d_in[5];
    const float* cvs_w     = (const float*)d_in[6];
    const float* c0_off_w  = (const float*)d_in[7];
    const float* c0_off_b  = (const float*)d_in[8];
    const float* c0_w      = (const float*)d_in[9];
    const float* cs_off_w  = (const float*)d_in[10];
    const float* cs_off_b  = (const float*)d_in[11];
    const float* cs_w      = (const float*)d_in[12];
    const float* conv1_w   = (const float*)d_in[13];
    const float* conv1_b   = (const float*)d_in[14];
    const float* conv2_w   = (const float*)d_in[15];
    const float* conv2_b   = (const float*)d_in[16];
    float* out = (float*)d_out;
    (void)d_ws; (void)ws_size;

    // weight transposes (tiny)
    prep_w_kernel<<<dim3(54),   256, 0, stream>>>(cv0_off_w, WT_A1, 18, 24, 9);
    prep_w_kernel<<<dim3(350),  256, 0, stream>>>(cvs_off_w, WT_A2, 50, 56, 25);
    prep_w_kernel<<<dim3(350),  256, 0, stream>>>(c0_off_w,  WT_B1, 50, 56, 25);
    prep_w_kernel<<<dim3(1274), 256, 0, stream>>>(cs_off_w,  WT_B2, 98, 104, 49);

    const int XB = 128 * HW;  // x batch stride
    const int AB = 64 * HW;   // ws activation batch stride

    // stage 1: offset convs from x
    offconv_kernel<3, 24><<<dim3(32, 3), 256, 0, stream>>>(
        x, 0, XB, WT_A1, cv0_off_b, OFF_A, 18, 1, 1);
    offconv_kernel<5, 56><<<dim3(32, 7), 256, 0, stream>>>(
        x + 64 * HW, 0, XB, WT_B1, c0_off_b, OFF_B, 50, 2, 1);

    // stage 1: deformable depthwise
    deform_kernel<3><<<dim3(128, 4), 256, 0, stream>>>(
        x, 0, XB, OFF_A, cv0_w, WS_A1, 1, 1);
    deform_kernel<5><<<dim3(128, 4), 256, 0, stream>>>(
        x + 64 * HW, 0, XB, OFF_B, c0_w, WS_B1, 2, 1);

    // stage 2: offset convs from stage-1 activations
    offconv_kernel<5, 56><<<dim3(32, 7), 256, 0, stream>>>(
        (const float*)nullptr, WS_A1, AB, WT_A2, cvs_off_b, OFF_A, 50, 6, 3);
    offconv_kernel<7, 104><<<dim3(32, 13), 256, 0, stream>>>(
        (const float*)nullptr, WS_B1, AB, WT_B2, cs_off_b, OFF_B, 98, 9, 3);

    // stage 2: deformable depthwise
    deform_kernel<5><<<dim3(128, 4), 256, 0, stream>>>(
        (const float*)nullptr, WS_A1, AB, OFF_A, cvs_w, WS_A2, 6, 3);
    deform_kernel<7><<<dim3(128, 4), 256, 0, stream>>>(
        (const float*)nullptr, WS_B1, AB, OFF_B, cs_w, WS_B2, 9, 3);

    // 1x1 convs + gating multiply
    final_kernel<<<dim3(16, 16, 2), 256, 0, stream>>>(
        x, WS_A2, WS_B2, conv1_w, conv1_b, conv2_w, conv2_b, out);
}

// Round 5
// 354.209 us; speedup vs baseline: 4.4439x; 4.4439x over previous
//
#include <hip/hip_runtime.h>
#include <hip/hip_bf16.h>

#define HW   4096

typedef __bf16 bf_t;
typedef __bf16 bf8_t __attribute__((ext_vector_type(8)));
typedef float  f4_t  __attribute__((ext_vector_type(4)));

// Static device workspace (element offsets into g_ws, in floats):
#define OFF_A  0              // 2*50*HW   = 409600 (18ch then 50ch offsets)
#define OFF_B  409600         // 2*98*HW   = 802816
#define WS_A1  1212416        // 2*64*HW   = 524288 each
#define WS_A2  1736704
#define WS_B1  2260992
#define WS_B2  2785280
#define XA_HI  3309568        // bf16[2*64*HW] = 262144 floats each
#define XA_LO  3571712
#define XB_HI  3833856
#define XB_LO  4096000
#define A1_HI  4358144
#define A1_LO  4620288
#define B1_HI  4882432
#define B1_LO  5144576
#define AW_A1  5406720        // k3:  9*2*128*8  bf16 -> 9216 fl
#define AW_B1  5415936        // k5: 25*4*128*8  bf16 -> 51200 fl
#define AW_A2  5467136        // k5: same
#define AW_B2  5518336        // k7: 49*8*128*8  bf16 -> 200704 fl
#define WS_TOT 5719040

__device__ float g_ws[WS_TOT];

__device__ __forceinline__ bf8_t bf8_zero() {
    bf8_t v;
#pragma unroll
    for (int j = 0; j < 8; ++j) v[j] = (bf_t)0.f;
    return v;
}

// ---------------------------------------------------------------------------
// fp32 NCHW (64ch, batch stride bstride) -> two bf16 NHWC buffers (hi, lo):
// a = hi + lo, hi = bf16(a), lo = bf16(a - hi).  grid (B, 64); block 256.
// ---------------------------------------------------------------------------
__global__ __launch_bounds__(256) void split_nhwc_kernel(
    const float* __restrict__ src_ext, int src_off, int bstride,
    int hi_off, int lo_off)
{
    const float* src = src_ext ? src_ext : (const float*)(g_ws + src_off);
    bf_t* dhi = (bf_t*)(g_ws + hi_off);
    bf_t* dlo = (bf_t*)(g_ws + lo_off);
    __shared__ float lds[64 * 68];
    const int b  = blockIdx.x;
    const int p0 = blockIdx.y * 64;
    const int t  = threadIdx.x;
    const int lane = t & 63, cw = t >> 6;
    const float* sb = src + (long)b * bstride;
#pragma unroll
    for (int i = 0; i < 16; ++i) {
        int ci = cw * 16 + i;
        lds[lane * 68 + ci] = sb[ci * HW + p0 + lane];
    }
    __syncthreads();
    for (int c = t; c < 512; c += 256) {
        int px = c >> 3, q = c & 7;
        bf8_t vh, vl;
#pragma unroll
        for (int j = 0; j < 8; ++j) {
            float a = lds[px * 68 + q * 8 + j];
            bf_t hcast = (bf_t)a;
            vh[j] = hcast;
            vl[j] = (bf_t)(a - (float)hcast);
        }
        long base = (((long)b * 4096 + p0 + px) * 64) + q * 8;
        *(bf8_t*)&dhi[base] = vh;
        *(bf8_t*)&dlo[base] = vl;
    }
}

// ---------------------------------------------------------------------------
// Weight pack: wg fp32 [Cout][64][K][K] -> bf16 A-fragment layout:
// aw[((tap*NCOT + cot)*2 + kh)*64 + lane][8] ; m=co=cot*16+(lane&15),
// k=ci=kh*32+(lane>>4)*8+j. Zero-padded beyond Cout.
// ---------------------------------------------------------------------------
template<int K, int NCOT>
__global__ __launch_bounds__(256) void prep_wA_kernel(const float* __restrict__ wg,
                                                      int aw_off, int Cout) {
    bf_t* aw = (bf_t*)(g_ws + aw_off);
    constexpr int KK = K * K;
    const int total = KK * NCOT * 2 * 64;
    for (int idx = blockIdx.x * 256 + threadIdx.x; idx < total; idx += gridDim.x * 256) {
        int lane = idx & 63;
        int kh   = (idx >> 6) & 1;
        int cot  = (idx >> 7) % NCOT;
        int tap  = idx / (128 * NCOT);
        int co   = cot * 16 + (lane & 15);
        int ci0  = kh * 32 + (lane >> 4) * 8;
        bf8_t v;
#pragma unroll
        for (int j = 0; j < 8; ++j) {
            float f = (co < Cout) ? wg[(co * 64 + ci0 + j) * KK + tap] : 0.f;
            v[j] = (bf_t)f;
        }
        *(bf8_t*)&aw[(long)idx * 8] = v;
    }
}

// ---------------------------------------------------------------------------
// MFMA implicit-GEMM conv with hi/lo split input for ~fp32 accuracy.
// grid (B*64 rows, 2); block 256 (4 waves = 4 pixel-tiles of 16).
// Each wave accumulates CPG co-tiles of 16.
// ---------------------------------------------------------------------------
template<int K, int DIL, int PAD, int NCOT, int CPG>
__global__ __launch_bounds__(256) void mfma_conv_kernel(
    int hi_off, int lo_off, int aw_off, const float* __restrict__ bias,
    int dst_off, int Cout)
{
    constexpr int COLS = 64 + 2 * PAD;
    const bf_t* shi = (const bf_t*)(g_ws + hi_off);
    const bf_t* slo = (const bf_t*)(g_ws + lo_off);
    const bf_t* aw  = (const bf_t*)(g_ws + aw_off);
    float* dst = g_ws + dst_off;
    __shared__ __align__(16) bf_t lds[2][COLS * 72];

    const int t    = threadIdx.x;
    const int lane = t & 63;
    const int wv   = t >> 6;            // pixel tile
    const int b    = blockIdx.x >> 6;
    const int h    = blockIdx.x & 63;
    const int ct0  = blockIdx.y * CPG;

    const int n0 = lane & 15;           // pixel within tile
    const int kq = lane >> 4;           // quad id

    f4_t acc[CPG];
#pragma unroll
    for (int i = 0; i < CPG; ++i) acc[i] = (f4_t){0.f, 0.f, 0.f, 0.f};

    for (int ky = 0; ky < K; ++ky) {
        const int ih = h - PAD + ky * DIL;
        __syncthreads();
        if ((unsigned)ih < 64u) {
            const long rowb = ((long)b * 4096 + ih * 64) * 64;
            for (int c = t; c < COLS * 8; c += 256) {
                int col = c >> 3, q = c & 7;
                int iw = col - PAD;
                bf8_t vh, vl;
                if ((unsigned)iw < 64u) {
                    vh = *(const bf8_t*)&shi[rowb + iw * 64 + q * 8];
                    vl = *(const bf8_t*)&slo[rowb + iw * 64 + q * 8];
                } else { vh = bf8_zero(); vl = bf8_zero(); }
                *(bf8_t*)&lds[0][col * 72 + q * 8] = vh;
                *(bf8_t*)&lds[1][col * 72 + q * 8] = vl;
            }
        } else {
            bf8_t z = bf8_zero();
            for (int c = t; c < COLS * 8; c += 256) {
                int col = c >> 3, q = c & 7;
                *(bf8_t*)&lds[0][col * 72 + q * 8] = z;
                *(bf8_t*)&lds[1][col * 72 + q * 8] = z;
            }
        }
        __syncthreads();
#pragma unroll
        for (int kx = 0; kx < K; ++kx) {
            const int tap = ky * K + kx;
            bf8_t afr[CPG][2];
#pragma unroll
            for (int ct = 0; ct < CPG; ++ct)
#pragma unroll
                for (int kh = 0; kh < 2; ++kh)
                    afr[ct][kh] = *(const bf8_t*)
                        &aw[((((long)tap * NCOT + ct0 + ct) * 2 + kh) * 64 + lane) * 8];
            const int colb = (wv * 16 + n0 + kx * DIL) * 72;
#pragma unroll
            for (int kh = 0; kh < 2; ++kh) {
                const bf8_t bh = *(const bf8_t*)&lds[0][colb + kh * 32 + kq * 8];
                const bf8_t bl = *(const bf8_t*)&lds[1][colb + kh * 32 + kq * 8];
#pragma unroll
                for (int ct = 0; ct < CPG; ++ct) {
                    acc[ct] = __builtin_amdgcn_mfma_f32_16x16x32_bf16(
                        afr[ct][kh], bh, acc[ct], 0, 0, 0);
                    acc[ct] = __builtin_amdgcn_mfma_f32_16x16x32_bf16(
                        afr[ct][kh], bl, acc[ct], 0, 0, 0);
                }
            }
        }
    }

    const int w = wv * 16 + n0;
#pragma unroll
    for (int ct = 0; ct < CPG; ++ct) {
#pragma unroll
        for (int r = 0; r < 4; ++r) {
            int co = (ct0 + ct) * 16 + kq * 4 + r;
            if (co < Cout)
                dst[((long)b * Cout + co) * HW + h * 64 + w] = acc[ct][r] + bias[co];
        }
    }
}

// ---------------------------------------------------------------------------
// Depthwise deformable sampling (fp32).
// ---------------------------------------------------------------------------
template<int K>
__global__ __launch_bounds__(256) void deform_kernel(
    const float* __restrict__ src_ext, int src_off, int bstride,
    int off_off, const float* __restrict__ wdw,
    int dst_off, int pad, int dil)
{
    constexpr int KK = K * K;
    const float* src = src_ext ? src_ext : (const float*)(g_ws + src_off);
    const float* off = g_ws + off_off;
    float*       dst = g_ws + dst_off;

    const int tid = threadIdx.x;
    const int w   = tid & 63;
    const int b   = blockIdx.x >> 6;
    const int h   = blockIdx.x & 63;
    const int c0  = (int)(blockIdx.y << 4) + ((tid >> 6) << 2);

    const float* offb = off + (long)b * (2 * KK) * HW + h * 64 + w;
    const float* sb   = src + (long)b * bstride + (long)c0 * HW;

    float acc[4] = {0.f, 0.f, 0.f, 0.f};

    for (int kk = 0; kk < KK; ++kk) {
        const float oy = offb[(2 * kk) * HW];
        const float ox = offb[(2 * kk + 1) * HW];
        const float py = oy + (float)(h - pad + (kk / K) * dil);
        const float px = ox + (float)(w - pad + (kk % K) * dil);
        const float fy = floorf(py), fx = floorf(px);
        const float ly = py - fy,    lx = px - fx;
        const int y0 = (int)fy, x0 = (int)fx;
        const int y1 = y0 + 1,  x1 = x0 + 1;
        const float vy0 = ((unsigned)y0 < 64u) ? 1.f : 0.f;
        const float vy1 = ((unsigned)y1 < 64u) ? 1.f : 0.f;
        const float vx0 = ((unsigned)x0 < 64u) ? 1.f : 0.f;
        const float vx1 = ((unsigned)x1 < 64u) ? 1.f : 0.f;
        const float w00 = (1.f - ly) * (1.f - lx) * vy0 * vx0;
        const float w01 = (1.f - ly) * lx         * vy0 * vx1;
        const float w10 = ly         * (1.f - lx) * vy1 * vx0;
        const float w11 = ly         * lx         * vy1 * vx1;
        const int y0c = min(max(y0, 0), 63), y1c = min(max(y1, 0), 63);
        const int x0c = min(max(x0, 0), 63), x1c = min(max(x1, 0), 63);
        const int i00 = y0c * 64 + x0c, i01 = y0c * 64 + x1c;
        const int i10 = y1c * 64 + x0c, i11 = y1c * 64 + x1c;
#pragma unroll
        for (int j = 0; j < 4; ++j) {
            const float* sc = sb + j * HW;
            float val = w00 * sc[i00] + w01 * sc[i01]
                      + w10 * sc[i10] + w11 * sc[i11];
            acc[j] = fmaf(wdw[(c0 + j) * KK + kk], val, acc[j]);
        }
    }

    float* dp = dst + ((long)b * 64 + c0) * HW + h * 64 + w;
#pragma unroll
    for (int j = 0; j < 4; ++j) dp[j * HW] = acc[j];
}

// ---------------------------------------------------------------------------
// Final: per-branch 1x1 conv (+bias), then out = x * result.  fp32 out.
// ---------------------------------------------------------------------------
__global__ __launch_bounds__(256) void final_kernel(
    const float* __restrict__ x,
    int aA_off, int aB_off,
    const float* __restrict__ w1, const float* __restrict__ b1,
    const float* __restrict__ w2, const float* __restrict__ b2,
    float* __restrict__ out)
{
    __shared__ float wlds[512];
    const int tid = threadIdx.x;
    const int p   = blockIdx.x * 256 + tid;
    const int co0 = blockIdx.y << 3;
    const int b   = blockIdx.z;
    const bool brB = (co0 >= 64);
    const int  cl0 = co0 & 63;
    const float* a  = g_ws + (brB ? aB_off : aA_off);
    const float* wg = brB ? w2 : w1;
    const float* bg = brB ? b2 : b1;

    for (int e = tid; e < 512; e += 256) {
        int ci = e >> 3, j = e & 7;
        wlds[e] = wg[(cl0 + j) * 64 + ci];
    }
    __syncthreads();

    float acc[8] = {0, 0, 0, 0, 0, 0, 0, 0};
    const float* ab = a + (long)b * 64 * HW + p;
    for (int ci = 0; ci < 64; ++ci) {
        const float av = ab[ci * HW];
        const float* wr = &wlds[ci * 8];
#pragma unroll
        for (int j = 0; j < 8; ++j) acc[j] = fmaf(av, wr[j], acc[j]);
    }

    const float* xb = x   + ((long)b * 128 + co0) * HW + p;
    float*       ob = out + ((long)b * 128 + co0) * HW + p;
#pragma unroll
    for (int j = 0; j < 8; ++j) {
        ob[j * HW] = (acc[j] + bg[cl0 + j]) * xb[j * HW];
    }
}

// ---------------------------------------------------------------------------
extern "C" void kernel_launch(void* const* d_in, const int* in_sizes, int n_in,
                              void* d_out, int out_size, void* d_ws, size_t ws_size,
                              hipStream_t stream) {
    const float* x         = (const float*)d_in[0];
    const float* cv0_off_w = (const float*)d_in[1];
    const float* cv0_off_b = (const float*)d_in[2];
    const float* cv0_w     = (const float*)d_in[3];
    const float* cvs_off_w = (const float*)d_in[4];
    const float* cvs_off_b = (const float*)d_in[5];
    const float* cvs_w     = (const float*)d_in[6];
    const float* c0_off_w  = (const float*)d_in[7];
    const float* c0_off_b  = (const float*)d_in[8];
    const float* c0_w      = (const float*)d_in[9];
    const float* cs_off_w  = (const float*)d_in[10];
    const float* cs_off_b  = (const float*)d_in[11];
    const float* cs_w      = (const float*)d_in[12];
    const float* conv1_w   = (const float*)d_in[13];
    const float* conv1_b   = (const float*)d_in[14];
    const float* conv2_w   = (const float*)d_in[15];
    const float* conv2_b   = (const float*)d_in[16];
    float* out = (float*)d_out;
    (void)d_ws; (void)ws_size;

    const int XB = 128 * HW;
    const int AB = 64 * HW;

    // weight packs (tiny)
    prep_wA_kernel<3, 2><<<dim3(9),   256, 0, stream>>>(cv0_off_w, AW_A1, 18);
    prep_wA_kernel<5, 4><<<dim3(50),  256, 0, stream>>>(c0_off_w,  AW_B1, 50);
    prep_wA_kernel<5, 4><<<dim3(50),  256, 0, stream>>>(cvs_off_w, AW_A2, 50);
    prep_wA_kernel<7, 8><<<dim3(196), 256, 0, stream>>>(cs_off_w,  AW_B2, 98);

    // hi/lo bf16 NHWC splits of x branches
    split_nhwc_kernel<<<dim3(2, 64), 256, 0, stream>>>(x,           0, XB, XA_HI, XA_LO);
    split_nhwc_kernel<<<dim3(2, 64), 256, 0, stream>>>(x + 64 * HW, 0, XB, XB_HI, XB_LO);

    // stage 1: offset convs (MFMA, split input)
    mfma_conv_kernel<3, 1, 1, 2, 1><<<dim3(128, 2), 256, 0, stream>>>(
        XA_HI, XA_LO, AW_A1, cv0_off_b, OFF_A, 18);
    mfma_conv_kernel<5, 1, 2, 4, 2><<<dim3(128, 2), 256, 0, stream>>>(
        XB_HI, XB_LO, AW_B1, c0_off_b, OFF_B, 50);

    // stage 1: deformable depthwise
    deform_kernel<3><<<dim3(128, 4), 256, 0, stream>>>(
        x, 0, XB, OFF_A, cv0_w, WS_A1, 1, 1);
    deform_kernel<5><<<dim3(128, 4), 256, 0, stream>>>(
        x + 64 * HW, 0, XB, OFF_B, c0_w, WS_B1, 2, 1);

    // hi/lo splits of stage-1 activations
    split_nhwc_kernel<<<dim3(2, 64), 256, 0, stream>>>(nullptr, WS_A1, AB, A1_HI, A1_LO);
    split_nhwc_kernel<<<dim3(2, 64), 256, 0, stream>>>(nullptr, WS_B1, AB, B1_HI, B1_LO);

    // stage 2: offset convs (MFMA, split input)
    mfma_conv_kernel<5, 3, 6, 4, 2><<<dim3(128, 2), 256, 0, stream>>>(
        A1_HI, A1_LO, AW_A2, cvs_off_b, OFF_A, 50);
    mfma_conv_kernel<7, 3, 9, 8, 4><<<dim3(128, 2), 256, 0, stream>>>(
        B1_HI, B1_LO, AW_B2, cs_off_b, OFF_B, 98);

    // stage 2: deformable depthwise
    deform_kernel<5><<<dim3(128, 4), 256, 0, stream>>>(
        nullptr, WS_A1, AB, OFF_A, cvs_w, WS_A2, 6, 3);
    deform_kernel<7><<<dim3(128, 4), 256, 0, stream>>>(
        nullptr, WS_B1, AB, OFF_B, cs_w, WS_B2, 9, 3);

    // 1x1 convs + gating multiply
    final_kernel<<<dim3(16, 16, 2), 256, 0, stream>>>(
        x, WS_A2, WS_B2, conv1_w, conv1_b, conv2_w, conv2_b, out);
}